// Round 13
// baseline (849.612 us; speedup 1.0000x reference)
//
#include <hip/hip_runtime.h>
#include <hip/hip_bf16.h>
#include <stdint.h>

// TreeLSTM fused, round 13: R12 pipeline with doubled per-CU residency.
// grid 512 (256 phases x 2 halves) -> 2 blocks/CU; waves_per_eu(4,4) keeps
// VGPR <=128 so 16 waves/CU are resident. Same counted-vmcnt + s_barrier
// pipeline; out stores normal (L2 line-merge) instead of nt.

typedef __attribute__((ext_vector_type(8))) short bf16x8;
typedef __attribute__((ext_vector_type(4))) float f4v;

#define N_ROWS 200000
#define TILES 12500     // N_ROWS / 16
#define PHASES 256
#define XSTR 258        // LDS row stride in floats (256 + 2) -> conflict-free

__device__ __forceinline__ bf16x8 pack8(f4v a, f4v b) {
    union { __hip_bfloat162 h2[4]; bf16x8 v; } u;
    u.h2[0] = __float22bfloat162_rn(make_float2(a.x, a.y));
    u.h2[1] = __float22bfloat162_rn(make_float2(a.z, a.w));
    u.h2[2] = __float22bfloat162_rn(make_float2(b.x, b.y));
    u.h2[3] = __float22bfloat162_rn(make_float2(b.z, b.w));
    return u.v;
}
__device__ __forceinline__ float fsig(float x) { return 1.0f / (1.0f + __expf(-x)); }
__device__ __forceinline__ float ftanh(float x) {
    float e = __expf(2.0f * x);
    return 1.0f - 2.0f / (e + 1.0f);
}

__global__ __launch_bounds__(512)
__attribute__((amdgpu_waves_per_eu(4, 4)))
void treelstm_main(const float* __restrict__ x,
                   const float* __restrict__ Uh,
                   const float* __restrict__ fc,
                   const float* __restrict__ W_iou,
                   const float* __restrict__ b_iou,
                   const float* __restrict__ W_f,
                   const float* __restrict__ b_f,
                   float* __restrict__ out) {
    __shared__ float xlds[2][16 * XSTR];     // 33 KB, double-buffered x tile

    const int tid   = threadIdx.x;
    const int lane  = tid & 63;
    const int w     = tid >> 6;              // wave 0..7
    const int q     = lane >> 4;
    const int bcol  = lane & 15;
    const int half  = blockIdx.x >> 8;       // width half (b, b+256 same XCD)
    const int phase = blockIdx.x & 255;      // row phase
    const int sl    = half * 8 + w;          // global slice 0..15
    const int kb    = sl * 16 + q * 4;       // lane's 4 output cols per gate
    const int C     = sl * 16 + bcol;        // W row for A-frag

    // ---- resident biases (16 VGPR) ----
    const f4v bi  = *(const f4v*)&b_iou[kb];
    const f4v bo  = *(const f4v*)&b_iou[256 + kb];
    const f4v bu  = *(const f4v*)&b_iou[512 + kb];
    const f4v bf4 = *(const f4v*)&b_f[kb];

    // ---- W fragments (compiler keeps/reloads from L1 as VGPR budget allows) ----
    // A-frag: A[row = lane&15 -> W-col C][k = ks*32 + q*8 + 0..7]
    bf16x8 wreg[32];
#pragma unroll
    for (int g = 0; g < 4; ++g) {
        const float* wr = (g < 3) ? (W_iou + (size_t)(g * 256 + C) * 256)
                                  : (W_f + (size_t)C * 256);
#pragma unroll
        for (int ks = 0; ks < 8; ++ks) {
            const f4v p0 = *(const f4v*)(wr + ks * 32 + q * 8);
            const f4v p1 = *(const f4v*)(wr + ks * 32 + q * 8 + 4);
            wreg[g * 8 + ks] = pack8(p0, p1);
        }
    }

    float* out_h = out;
    float* out_c = out + (size_t)N_ROWS * 256;
    float* out_f = out + 2 * (size_t)N_ROWS * 256;

    // stage tile t's x into LDS buf: wave w stages rows 2w, 2w+1 (2 x 1KB)
    auto STAGE = [&](int t, int buf) {
#pragma unroll
        for (int rr = 0; rr < 2; ++rr) {
            const int r = 2 * w + rr;
            const float* src = x + (size_t)(t * 16 + r) * 256 + lane * 4;
            __builtin_amdgcn_global_load_lds(
                (const __attribute__((address_space(1))) uint32_t*)src,
                (__attribute__((address_space(3))) uint32_t*)&xlds[buf][r * XSTR],
                16, 0, 0);
        }
        __builtin_amdgcn_sched_barrier(0);
    };

    f4v uhi, uho, uhu, fcv;
    auto LOADUH = [&](int tt) {
        const float* uh = Uh + (size_t)(tt * 16 + bcol) * 768 + kb;
        uhi = __builtin_nontemporal_load((const f4v*)uh);
        uho = __builtin_nontemporal_load((const f4v*)(uh + 256));
        uhu = __builtin_nontemporal_load((const f4v*)(uh + 512));
        fcv = __builtin_nontemporal_load((const f4v*)(fc + (size_t)(tt * 16 + bcol) * 256 + kb));
    };

    // ---- prologue ----
    int t = phase, buf = 0;
    STAGE(t, 0);
    LOADUH(t);
    asm volatile("s_waitcnt vmcnt(4)" ::: "memory");   // x(t) in LDS; uh in flight
    __builtin_amdgcn_s_barrier();
    __builtin_amdgcn_sched_barrier(0);

    while (true) {
        const int tn = t + PHASES;
        const bool more = (tn < TILES);
        if (more) STAGE(tn, buf ^ 1);       // safe: no wave reads buf^1 anymore

        // ---- MFMA from LDS (acc = bias-init); pack inline ----
        f4v acc0 = bi, acc1 = bo, acc2 = bu, acc3 = bf4;
#pragma unroll
        for (int ks = 0; ks < 8; ++ks) {
            const f4v p0 = *(const f4v*)&xlds[buf][bcol * XSTR + ks * 32 + q * 8];
            const f4v p1 = *(const f4v*)&xlds[buf][bcol * XSTR + ks * 32 + q * 8 + 4];
            const bf16x8 xf = pack8(p0, p1);
            acc0 = __builtin_amdgcn_mfma_f32_16x16x32_bf16(wreg[0 * 8 + ks], xf, acc0, 0, 0, 0);
            acc1 = __builtin_amdgcn_mfma_f32_16x16x32_bf16(wreg[1 * 8 + ks], xf, acc1, 0, 0, 0);
            acc2 = __builtin_amdgcn_mfma_f32_16x16x32_bf16(wreg[2 * 8 + ks], xf, acc2, 0, 0, 0);
            acc3 = __builtin_amdgcn_mfma_f32_16x16x32_bf16(wreg[3 * 8 + ks], xf, acc3, 0, 0, 0);
        }

        // ---- epilogue: drains uh(t) only (stage(tn) stays in flight) ----
        const int n = t * 16 + bcol;
        f4v cc, hh, ff;
        cc.x = fsig(acc0.x + uhi.x) * ftanh(acc2.x + uhu.x) + fcv.x;
        cc.y = fsig(acc0.y + uhi.y) * ftanh(acc2.y + uhu.y) + fcv.y;
        cc.z = fsig(acc0.z + uhi.z) * ftanh(acc2.z + uhu.z) + fcv.z;
        cc.w = fsig(acc0.w + uhi.w) * ftanh(acc2.w + uhu.w) + fcv.w;
        hh.x = fsig(acc1.x + uho.x) * ftanh(cc.x);
        hh.y = fsig(acc1.y + uho.y) * ftanh(cc.y);
        hh.z = fsig(acc1.z + uho.z) * ftanh(cc.z);
        hh.w = fsig(acc1.w + uho.w) * ftanh(cc.w);
        ff.x = acc3.x; ff.y = acc3.y; ff.z = acc3.z; ff.w = acc3.w;
        const size_t oidx = (size_t)n * 256 + kb;
        *(f4v*)(out_h + oidx) = hh;         // normal stores: L2 merges the
        *(f4v*)(out_c + oidx) = cc;         // sibling-wave 64B partials
        *(f4v*)(out_f + oidx) = ff;

        if (!more) break;

        LOADUH(tn);                          // uh(t+1): flies across the barrier
        // drain EXACTLY the 2 stage loads (oldest); stores + uh stay in flight
        asm volatile("s_waitcnt vmcnt(7)" ::: "memory");
        __builtin_amdgcn_s_barrier();
        __builtin_amdgcn_sched_barrier(0);
        t = tn; buf ^= 1;
    }
}

extern "C" void kernel_launch(void* const* d_in, const int* in_sizes, int n_in,
                              void* d_out, int out_size, void* d_ws, size_t ws_size,
                              hipStream_t stream) {
    const float* x     = (const float*)d_in[0];
    const float* Uh    = (const float*)d_in[1];
    const float* fc    = (const float*)d_in[2];
    const float* W_iou = (const float*)d_in[3];
    const float* b_iou = (const float*)d_in[4];
    const float* W_f   = (const float*)d_in[5];
    const float* b_f   = (const float*)d_in[6];
    float* out = (float*)d_out;

    treelstm_main<<<512, 512, 0, stream>>>(x, Uh, fc, W_iou, b_iou, W_f, b_f, out);
}

// Round 14
// 362.840 us; speedup vs baseline: 2.3416x; 2.3416x over previous
//
#include <hip/hip_runtime.h>
#include <hip/hip_bf16.h>
#include <stdint.h>

// TreeLSTM fused, round 14: R12 pipeline deepened to 2 tiles ahead.
// Keep R12's proven point: 256 blocks (128 phases x 2 XCD-paired halves),
// 512 thr, waves_per_eu(2,2) so W stays register/L1-resident (R13 showed
// waves_per_eu(4,4) -> VGPR 64 -> W refetch -> FETCH 2.6GB regression).
// New: 4-buffer LDS x-stage + two named uh register sets, 2x-unrolled pair
// loop with tail-clamped (unconditional) loads so every vmcnt immediate is
// exact. Every consumer's data is issued 2 tiles (~2 latencies) ahead ->
// waits ~0. Normal stores (R13: WRITE 790->682 MB vs nt).

typedef __attribute__((ext_vector_type(8))) short bf16x8;
typedef __attribute__((ext_vector_type(4))) float f4v;

#define N_ROWS 200000
#define TILES 12500     // N_ROWS / 16
#define XSTR 258        // LDS row stride in floats (256 + 2) -> conflict-free
#define VMW(N) asm volatile("s_waitcnt vmcnt(" #N ")" ::: "memory")
#define SBR() __builtin_amdgcn_sched_barrier(0)

__device__ __forceinline__ bf16x8 pack8(f4v a, f4v b) {
    union { __hip_bfloat162 h2[4]; bf16x8 v; } u;
    u.h2[0] = __float22bfloat162_rn(make_float2(a.x, a.y));
    u.h2[1] = __float22bfloat162_rn(make_float2(a.z, a.w));
    u.h2[2] = __float22bfloat162_rn(make_float2(b.x, b.y));
    u.h2[3] = __float22bfloat162_rn(make_float2(b.z, b.w));
    return u.v;
}
__device__ __forceinline__ float fsig(float x) { return 1.0f / (1.0f + __expf(-x)); }
__device__ __forceinline__ float ftanh(float x) {
    float e = __expf(2.0f * x);
    return 1.0f - 2.0f / (e + 1.0f);
}

__global__ __launch_bounds__(512)
__attribute__((amdgpu_waves_per_eu(2, 2)))
void treelstm_main(const float* __restrict__ x,
                   const float* __restrict__ Uh,
                   const float* __restrict__ fc,
                   const float* __restrict__ W_iou,
                   const float* __restrict__ b_iou,
                   const float* __restrict__ W_f,
                   const float* __restrict__ b_f,
                   float* __restrict__ out) {
    __shared__ float xlds[4][16 * XSTR];     // 66 KB, quad-buffered x tiles

    const int tid   = threadIdx.x;
    const int lane  = tid & 63;
    const int w     = tid >> 6;              // wave 0..7
    const int q     = lane >> 4;
    const int bcol  = lane & 15;
    const int half  = blockIdx.x >> 7;       // width half (b, b+128 same XCD)
    const int phase = blockIdx.x & 127;      // row phase
    const int sl    = half * 8 + w;          // global slice 0..15
    const int kb    = sl * 16 + q * 4;       // lane's 4 output cols per gate
    const int C     = sl * 16 + bcol;        // W row for A-frag

    // ---- resident biases ----
    const f4v bI = *(const f4v*)&b_iou[kb];
    const f4v bO = *(const f4v*)&b_iou[256 + kb];
    const f4v bU = *(const f4v*)&b_iou[512 + kb];
    const f4v bF = *(const f4v*)&b_f[kb];

    // ---- W fragments, loaded once (A[row=lane&15 -> col C][k=ks*32+q*8..]) ----
    bf16x8 wreg[32];
#pragma unroll
    for (int g = 0; g < 4; ++g) {
        const float* wr = (g < 3) ? (W_iou + (size_t)(g * 256 + C) * 256)
                                  : (W_f + (size_t)C * 256);
#pragma unroll
        for (int ks = 0; ks < 8; ++ks) {
            const f4v p0 = *(const f4v*)(wr + ks * 32 + q * 8);
            const f4v p1 = *(const f4v*)(wr + ks * 32 + q * 8 + 4);
            wreg[g * 8 + ks] = pack8(p0, p1);
        }
    }
    VMW(0); SBR();                           // clean vmcnt baseline for pipeline

    float* out_h = out;
    float* out_c = out + (size_t)N_ROWS * 256;
    float* out_f = out + 2 * (size_t)N_ROWS * 256;

    const int cnt   = (TILES - phase + 127) >> 7;   // 97 or 98 tiles
    const int pairs = cnt >> 1;
    const int tail  = cnt & 1;

    // tile number for index j, clamped so tail loads are unconditional
    auto TN = [&](int j) { const int jj = (j < cnt) ? j : (cnt - 1);
                           return phase + (jj << 7); };

    auto STAGE = [&](int t, int rb) {        // 2 x global_load_lds (16B)
#pragma unroll
        for (int rr = 0; rr < 2; ++rr) {
            const int r = 2 * w + rr;
            const float* src = x + (size_t)(t * 16 + r) * 256 + lane * 4;
            __builtin_amdgcn_global_load_lds(
                (const __attribute__((address_space(1))) uint32_t*)src,
                (__attribute__((address_space(3))) uint32_t*)&xlds[rb][r * XSTR],
                16, 0, 0);
        }
        SBR();
    };

    auto LOADUH = [&](int t, f4v& ui, f4v& uo, f4v& uu, f4v& fv) {   // 4 loads
        const float* uh = Uh + (size_t)(t * 16 + bcol) * 768 + kb;
        ui = __builtin_nontemporal_load((const f4v*)uh);
        uo = __builtin_nontemporal_load((const f4v*)(uh + 256));
        uu = __builtin_nontemporal_load((const f4v*)(uh + 512));
        fv = __builtin_nontemporal_load((const f4v*)(fc + (size_t)(t * 16 + bcol) * 256 + kb));
    };

    auto WORK = [&](int rb, int t, const f4v& ui, const f4v& uo,
                    const f4v& uu, const f4v& fv) {  // MFMA + epilogue (3 stores)
        f4v a0 = bI, a1 = bO, a2 = bU, a3 = bF;
#pragma unroll
        for (int ks = 0; ks < 8; ++ks) {
            const f4v p0 = *(const f4v*)&xlds[rb][bcol * XSTR + ks * 32 + q * 8];
            const f4v p1 = *(const f4v*)&xlds[rb][bcol * XSTR + ks * 32 + q * 8 + 4];
            const bf16x8 xf = pack8(p0, p1);
            a0 = __builtin_amdgcn_mfma_f32_16x16x32_bf16(wreg[0 * 8 + ks], xf, a0, 0, 0, 0);
            a1 = __builtin_amdgcn_mfma_f32_16x16x32_bf16(wreg[1 * 8 + ks], xf, a1, 0, 0, 0);
            a2 = __builtin_amdgcn_mfma_f32_16x16x32_bf16(wreg[2 * 8 + ks], xf, a2, 0, 0, 0);
            a3 = __builtin_amdgcn_mfma_f32_16x16x32_bf16(wreg[3 * 8 + ks], xf, a3, 0, 0, 0);
        }
        const int n = t * 16 + bcol;
        f4v cc, hh, ff;
        cc.x = fsig(a0.x + ui.x) * ftanh(a2.x + uu.x) + fv.x;
        cc.y = fsig(a0.y + ui.y) * ftanh(a2.y + uu.y) + fv.y;
        cc.z = fsig(a0.z + ui.z) * ftanh(a2.z + uu.z) + fv.z;
        cc.w = fsig(a0.w + ui.w) * ftanh(a2.w + uu.w) + fv.w;
        hh.x = fsig(a1.x + uo.x) * ftanh(cc.x);
        hh.y = fsig(a1.y + uo.y) * ftanh(cc.y);
        hh.z = fsig(a1.z + uo.z) * ftanh(cc.z);
        hh.w = fsig(a1.w + uo.w) * ftanh(cc.w);
        ff.x = a3.x; ff.y = a3.y; ff.z = a3.z; ff.w = a3.w;
        const size_t oidx = (size_t)n * 256 + kb;
        *(f4v*)(out_h + oidx) = hh;
        *(f4v*)(out_c + oidx) = cc;
        *(f4v*)(out_f + oidx) = ff;
    };

    f4v uhiA, uhoA, uhuA, fcvA, uhiB, uhoB, uhuB, fcvB;

    // ---- prologue: stage+load tiles j=0,1 (always real; cnt >= 97) ----
    STAGE(TN(0), 0); LOADUH(TN(0), uhiA, uhoA, uhuA, fcvA);
    STAGE(TN(1), 1); LOADUH(TN(1), uhiB, uhoB, uhuB, fcvB);
    // outstanding: S0(2) A0(4) S1(2) B1(4) = 12 -> drain S0
    VMW(10);
    __builtin_amdgcn_s_barrier(); SBR();

    for (int i = 0; i < pairs; ++i) {
        const int j0 = 2 * i;
        const int rA = (i & 1) ? 2 : 0;      // read buffers this pair
        const int rB = rA + 1;
        const int sA = (i & 1) ? 0 : 2;      // stage buffers this pair
        const int sB = sA + 1;

        // ---- half 1: tile j0 ----
        STAGE(TN(j0 + 2), sA);
        WORK(rA, TN(j0), uhiA, uhoA, uhuA, fcvA);   // compiler drains uh(j0)
        LOADUH(TN(j0 + 2), uhiA, uhoA, uhuA, fcvA);
        // steady outstanding 18, oldest = prev-half stage(2) -> leave 16
        // (first pair: no older stores yet -> 15 outstanding -> leave 13)
        if (i == 0) { VMW(13); } else { VMW(16); }
        __builtin_amdgcn_s_barrier(); SBR();

        // ---- half 2: tile j0+1 ----
        STAGE(TN(j0 + 3), sB);
        WORK(rB, TN(j0 + 1), uhiB, uhoB, uhuB, fcvB);
        LOADUH(TN(j0 + 3), uhiB, uhoB, uhuB, fcvB);
        VMW(16);
        __builtin_amdgcn_s_barrier(); SBR();
    }

    if (tail) {                              // odd cnt: last tile, buf by parity
        const int rA = (pairs & 1) ? 2 : 0;
        WORK(rA, TN(cnt - 1), uhiA, uhoA, uhuA, fcvA);
    }
}

extern "C" void kernel_launch(void* const* d_in, const int* in_sizes, int n_in,
                              void* d_out, int out_size, void* d_ws, size_t ws_size,
                              hipStream_t stream) {
    const float* x     = (const float*)d_in[0];
    const float* Uh    = (const float*)d_in[1];
    const float* fc    = (const float*)d_in[2];
    const float* W_iou = (const float*)d_in[3];
    const float* b_iou = (const float*)d_in[4];
    const float* W_f   = (const float*)d_in[5];
    const float* b_f   = (const float*)d_in[6];
    float* out = (float*)d_out;

    treelstm_main<<<256, 512, 0, stream>>>(x, Uh, fc, W_iou, b_iou, W_f, b_f, out);
}